// Round 1
// baseline (686.668 us; speedup 1.0000x reference)
//
#include <hip/hip_runtime.h>
#include <math.h>

#define N_NODES 50000
#define N_EDGES 800000
#define IN_DIM 256
#define HID 32
#define HEADS 8
#define HC 256
#define OUT_DIM 64
#define NEG_SLOPE 0.2f

static __device__ __forceinline__ float lrelu(float v) {
    return v > 0.f ? v : NEG_SLOPE * v;
}
static __device__ __forceinline__ float elu_f(float v) {
    return v > 0.f ? v : (__expf(v) - 1.f);
}

// ---------------- CSR build ----------------

__global__ void hist_kernel(const int* __restrict__ dst, int* __restrict__ cnt, int e) {
    int i = blockIdx.x * blockDim.x + threadIdx.x;
    if (i < e) atomicAdd(&cnt[dst[i]], 1);
}

// Exclusive scan of counts[n] -> offsets[n+1]; also writes cursor[i]=offsets[i].
// counts and cursor may alias (each thread reads its own element before writing it).
__global__ __launch_bounds__(1024) void scan_kernel(const int* __restrict__ counts,
                                                    int* __restrict__ offsets,
                                                    int* __restrict__ cursor, int n) {
    __shared__ int buf[1024];
    __shared__ int carry_s;
    int t = threadIdx.x;
    if (t == 0) carry_s = 0;
    __syncthreads();
    for (int base = 0; base < n; base += 1024) {
        int i = base + t;
        int v = (i < n) ? counts[i] : 0;
        buf[t] = v;
        __syncthreads();
        for (int off = 1; off < 1024; off <<= 1) {
            int add = (t >= off) ? buf[t - off] : 0;
            __syncthreads();
            buf[t] += add;
            __syncthreads();
        }
        int carry = carry_s;
        int excl = carry + buf[t] - v;
        if (i < n) { offsets[i] = excl; cursor[i] = excl; }
        __syncthreads();
        if (t == 0) carry_s = carry + buf[1023];
        __syncthreads();
    }
    if (t == 0) offsets[n] = carry_s;
}

__global__ void scatter_kernel(const int* __restrict__ src, const int* __restrict__ dst,
                               int* __restrict__ cursor, int* __restrict__ csr_src, int e) {
    int i = blockIdx.x * blockDim.x + threadIdx.x;
    if (i < e) {
        int p = atomicAdd(&cursor[dst[i]], 1);
        csr_src[p] = src[i];
    }
}

// ---------------- GEMMs ----------------

// X[M x 256] @ {Wl,Wr}[256 x 256] + {bl,br} -> Yl,Yr [M x 256]
__global__ __launch_bounds__(256) void gemm_dual_256(
    const float* __restrict__ X,
    const float* __restrict__ Wl, const float* __restrict__ bl,
    const float* __restrict__ Wr, const float* __restrict__ br,
    float* __restrict__ Yl, float* __restrict__ Yr, int M) {
    __shared__ float As[16][64];
    __shared__ float Bls[16][64];
    __shared__ float Brs[16][64];
    int tid = threadIdx.x;
    int tx = tid & 15, ty = tid >> 4;
    int row0 = blockIdx.y * 64;
    int col0 = blockIdx.x * 64;
    float accl[4][4] = {{0.f}};
    float accr[4][4] = {{0.f}};
    int ar = tid >> 2;
    int ak = (tid & 3) << 2;
    int bk = tid >> 4;
    int bn = (tid & 15) << 2;

    for (int k0 = 0; k0 < 256; k0 += 16) {
        float4 av = make_float4(0.f, 0.f, 0.f, 0.f);
        if (row0 + ar < M)
            av = *(const float4*)(X + (size_t)(row0 + ar) * 256 + k0 + ak);
        As[ak + 0][ar] = av.x;
        As[ak + 1][ar] = av.y;
        As[ak + 2][ar] = av.z;
        As[ak + 3][ar] = av.w;
        *(float4*)&Bls[bk][bn] = *(const float4*)(Wl + (size_t)(k0 + bk) * 256 + col0 + bn);
        *(float4*)&Brs[bk][bn] = *(const float4*)(Wr + (size_t)(k0 + bk) * 256 + col0 + bn);
        __syncthreads();
#pragma unroll
        for (int k = 0; k < 16; ++k) {
            float4 a4 = *(float4*)&As[k][ty * 4];
            float4 b4l = *(float4*)&Bls[k][tx * 4];
            float4 b4r = *(float4*)&Brs[k][tx * 4];
            float a[4] = {a4.x, a4.y, a4.z, a4.w};
            float bl4[4] = {b4l.x, b4l.y, b4l.z, b4l.w};
            float br4[4] = {b4r.x, b4r.y, b4r.z, b4r.w};
#pragma unroll
            for (int i = 0; i < 4; ++i)
#pragma unroll
                for (int j = 0; j < 4; ++j) {
                    accl[i][j] = fmaf(a[i], bl4[j], accl[i][j]);
                    accr[i][j] = fmaf(a[i], br4[j], accr[i][j]);
                }
        }
        __syncthreads();
    }
#pragma unroll
    for (int i = 0; i < 4; ++i) {
        int row = row0 + ty * 4 + i;
        if (row < M) {
            int col = col0 + tx * 4;
            float4 ol, orr;
            ol.x = accl[i][0] + bl[col + 0];
            ol.y = accl[i][1] + bl[col + 1];
            ol.z = accl[i][2] + bl[col + 2];
            ol.w = accl[i][3] + bl[col + 3];
            orr.x = accr[i][0] + br[col + 0];
            orr.y = accr[i][1] + br[col + 1];
            orr.z = accr[i][2] + br[col + 2];
            orr.w = accr[i][3] + br[col + 3];
            *(float4*)(Yl + (size_t)row * 256 + col) = ol;
            *(float4*)(Yr + (size_t)row * 256 + col) = orr;
        }
    }
}

// X[M x 256] @ {Wl,Wr}[256 x 32] + {bl,br} -> Yl,Yr [M x 32]
__global__ __launch_bounds__(256) void gemm_dual_32(
    const float* __restrict__ X,
    const float* __restrict__ Wl, const float* __restrict__ bl,
    const float* __restrict__ Wr, const float* __restrict__ br,
    float* __restrict__ Yl, float* __restrict__ Yr, int M) {
    __shared__ float As[16][64];
    __shared__ float B2l[16][32];
    __shared__ float B2r[16][32];
    int tid = threadIdx.x;
    int tx = tid & 31;
    int ty = tid >> 5;
    int row0 = blockIdx.x * 64;
    float accl[8] = {0.f};
    float accr[8] = {0.f};
    int ar = tid >> 2;
    int ak = (tid & 3) << 2;

    for (int k0 = 0; k0 < 256; k0 += 16) {
        float4 av = make_float4(0.f, 0.f, 0.f, 0.f);
        if (row0 + ar < M)
            av = *(const float4*)(X + (size_t)(row0 + ar) * 256 + k0 + ak);
        As[ak + 0][ar] = av.x;
        As[ak + 1][ar] = av.y;
        As[ak + 2][ar] = av.z;
        As[ak + 3][ar] = av.w;
        if (tid < 128) {
            int bk2 = tid >> 3, bn2 = (tid & 7) << 2;
            *(float4*)&B2l[bk2][bn2] = *(const float4*)(Wl + (size_t)(k0 + bk2) * 32 + bn2);
        } else {
            int t2 = tid - 128;
            int bk2 = t2 >> 3, bn2 = (t2 & 7) << 2;
            *(float4*)&B2r[bk2][bn2] = *(const float4*)(Wr + (size_t)(k0 + bk2) * 32 + bn2);
        }
        __syncthreads();
#pragma unroll
        for (int k = 0; k < 16; ++k) {
            float blv = B2l[k][tx];
            float brv = B2r[k][tx];
#pragma unroll
            for (int i = 0; i < 8; ++i) {
                float a = As[k][ty * 8 + i];
                accl[i] = fmaf(a, blv, accl[i]);
                accr[i] = fmaf(a, brv, accr[i]);
            }
        }
        __syncthreads();
    }
#pragma unroll
    for (int i = 0; i < 8; ++i) {
        int row = row0 + ty * 8 + i;
        if (row < M) {
            Yl[(size_t)row * 32 + tx] = accl[i] + bl[tx];
            Yr[(size_t)row * 32 + tx] = accr[i] + br[tx];
        }
    }
}

// ---------------- attention/aggregation ----------------

// One wave (64 lanes) per dst node; lane owns 4 consecutive channels of 256.
// Online softmax over incoming edges; writes h1 = elu(agg + bias).
__global__ __launch_bounds__(256) void conv1_agg(
    const float* __restrict__ xl, const float* __restrict__ xr,
    const float* __restrict__ att, const float* __restrict__ bias,
    const int* __restrict__ offsets, const int* __restrict__ csr_src,
    float* __restrict__ hout, int n) {
    int g = (blockIdx.x * blockDim.x + threadIdx.x) >> 6;
    if (g >= n) return;
    int lane = threadIdx.x & 63;
    int c0 = lane << 2;
    float4 xr4 = *(const float4*)(xr + (size_t)g * 256 + c0);
    float4 at4 = *(const float4*)(att + c0);
    float b0 = bias[c0 + 0], b1 = bias[c0 + 1], b2 = bias[c0 + 2], b3 = bias[c0 + 3];
    int beg = offsets[g], end = offsets[g + 1];
    float m = -INFINITY, denom = 0.f;
    float4 acc = make_float4(0.f, 0.f, 0.f, 0.f);
    for (int j = beg; j < end; ++j) {
        int s = csr_src[j];
        float4 a4 = *(const float4*)(xl + (size_t)s * 256 + c0);
        float p = at4.x * lrelu(a4.x + xr4.x) + at4.y * lrelu(a4.y + xr4.y) +
                  at4.z * lrelu(a4.z + xr4.z) + at4.w * lrelu(a4.w + xr4.w);
        // reduce across the 8 lanes of this head (lanes grouped by 8)
        p += __shfl_xor(p, 1);
        p += __shfl_xor(p, 2);
        p += __shfl_xor(p, 4);
        float mn = fmaxf(m, p);
        float f = __expf(m - mn);
        float e = __expf(p - mn);
        acc.x = fmaf(acc.x, f, e * a4.x);
        acc.y = fmaf(acc.y, f, e * a4.y);
        acc.z = fmaf(acc.z, f, e * a4.z);
        acc.w = fmaf(acc.w, f, e * a4.w);
        denom = fmaf(denom, f, e);
        m = mn;
    }
    float inv = 1.f / (denom + 1e-16f);
    float4 o;
    o.x = elu_f(fmaf(acc.x, inv, b0));
    o.y = elu_f(fmaf(acc.y, inv, b1));
    o.z = elu_f(fmaf(acc.z, inv, b2));
    o.w = elu_f(fmaf(acc.w, inv, b3));
    *(float4*)(hout + (size_t)g * 256 + c0) = o;
}

// Half-wave (32 lanes) per dst node; lane owns 1 of 32 channels (heads=1).
__global__ __launch_bounds__(256) void conv2_agg(
    const float* __restrict__ xl, const float* __restrict__ xr,
    const float* __restrict__ att, const float* __restrict__ bias,
    const int* __restrict__ offsets, const int* __restrict__ csr_src,
    float* __restrict__ hout, int n) {
    int g = (blockIdx.x * blockDim.x + threadIdx.x) >> 5;
    if (g >= n) return;
    int sl = threadIdx.x & 31;
    float xrv = xr[(size_t)g * 32 + sl];
    float atv = att[sl];
    float bv = bias[sl];
    int beg = offsets[g], end = offsets[g + 1];
    float m = -INFINITY, denom = 0.f, acc = 0.f;
    for (int j = beg; j < end; ++j) {
        int s = csr_src[j];
        float a = xl[(size_t)s * 32 + sl];
        float p = atv * lrelu(a + xrv);
        p += __shfl_xor(p, 1);
        p += __shfl_xor(p, 2);
        p += __shfl_xor(p, 4);
        p += __shfl_xor(p, 8);
        p += __shfl_xor(p, 16);
        float mn = fmaxf(m, p);
        float f = __expf(m - mn);
        float e = __expf(p - mn);
        acc = fmaf(acc, f, e * a);
        denom = fmaf(denom, f, e);
        m = mn;
    }
    float inv = 1.f / (denom + 1e-16f);
    hout[(size_t)g * 32 + sl] = elu_f(fmaf(acc, inv, bv));
}

// ---------------- final linear: h2[N x 32] @ W[32 x 64] + b ----------------

__global__ __launch_bounds__(256) void final_linear(
    const float* __restrict__ h, const float* __restrict__ W,
    const float* __restrict__ b, float* __restrict__ out, int n) {
    __shared__ float Ws[32][64];
    __shared__ float Hs[16][32];
    int tid = threadIdx.x;
    int node0 = blockIdx.x * 16;
    ((float4*)&Ws[0][0])[tid] = ((const float4*)W)[tid];
    ((float4*)&Ws[0][0])[tid + 256] = ((const float4*)W)[tid + 256];
    if (tid < 128) {
        int nd = node0 + (tid >> 3);
        if (nd < n) ((float4*)&Hs[0][0])[tid] = ((const float4*)h)[(size_t)node0 * 8 + tid];
    }
    __syncthreads();
    int i = tid >> 4;
    int j4 = (tid & 15) << 2;
    int node = node0 + i;
    if (node >= n) return;
    float4 acc;
    acc.x = b[j4 + 0];
    acc.y = b[j4 + 1];
    acc.z = b[j4 + 2];
    acc.w = b[j4 + 3];
#pragma unroll
    for (int k = 0; k < 32; ++k) {
        float hv = Hs[i][k];
        float4 w4 = *(float4*)&Ws[k][j4];
        acc.x = fmaf(hv, w4.x, acc.x);
        acc.y = fmaf(hv, w4.y, acc.y);
        acc.z = fmaf(hv, w4.z, acc.z);
        acc.w = fmaf(hv, w4.w, acc.w);
    }
    *(float4*)(out + (size_t)node * 64 + j4) = acc;
}

// ---------------- launch ----------------

extern "C" void kernel_launch(void* const* d_in, const int* in_sizes, int n_in,
                              void* d_out, int out_size, void* d_ws, size_t ws_size,
                              hipStream_t stream) {
    const float* x    = (const float*)d_in[0];
    const int*   ei   = (const int*)d_in[1];
    const float* W1l  = (const float*)d_in[2];
    const float* b1l  = (const float*)d_in[3];
    const float* W1r  = (const float*)d_in[4];
    const float* b1r  = (const float*)d_in[5];
    const float* att1 = (const float*)d_in[6];
    const float* bias1= (const float*)d_in[7];
    const float* W2l  = (const float*)d_in[8];
    const float* b2l  = (const float*)d_in[9];
    const float* W2r  = (const float*)d_in[10];
    const float* b2r  = (const float*)d_in[11];
    const float* att2 = (const float*)d_in[12];
    const float* bias2= (const float*)d_in[13];
    const float* Wlin = (const float*)d_in[14];
    const float* blin = (const float*)d_in[15];
    float* out = (float*)d_out;

    char* p = (char*)d_ws;
    auto alloc = [&](size_t bytes) {
        char* r = p;
        p += (bytes + 255) & ~(size_t)255;
        return r;
    };
    int* offsets = (int*)alloc((size_t)(N_NODES + 1) * 4);
    int* cursor  = (int*)alloc((size_t)N_NODES * 4);       // doubles as counts
    int* csr_src = (int*)alloc((size_t)N_EDGES * 4);
    float* xl1 = (float*)alloc((size_t)N_NODES * 256 * 4);
    float* xr1 = (float*)alloc((size_t)N_NODES * 256 * 4);
    float* h1  = (float*)alloc((size_t)N_NODES * 256 * 4);
    // conv2 buffers overlay xr1's region (xr1 dead after conv1_agg)
    float* xl2 = xr1;
    float* xr2 = xr1 + (size_t)N_NODES * 32;
    float* h2  = xr1 + (size_t)N_NODES * 64;

    const int* srcp = ei;
    const int* dstp = ei + N_EDGES;

    hipMemsetAsync(cursor, 0, (size_t)N_NODES * 4, stream);
    hist_kernel<<<(N_EDGES + 255) / 256, 256, 0, stream>>>(dstp, cursor, N_EDGES);
    scan_kernel<<<1, 1024, 0, stream>>>(cursor, offsets, cursor, N_NODES);
    scatter_kernel<<<(N_EDGES + 255) / 256, 256, 0, stream>>>(srcp, dstp, cursor, csr_src, N_EDGES);

    dim3 g1(4, (N_NODES + 63) / 64);
    gemm_dual_256<<<g1, 256, 0, stream>>>(x, W1l, b1l, W1r, b1r, xl1, xr1, N_NODES);
    conv1_agg<<<(N_NODES * 64 + 255) / 256, 256, 0, stream>>>(xl1, xr1, att1, bias1,
                                                              offsets, csr_src, h1, N_NODES);
    gemm_dual_32<<<(N_NODES + 63) / 64, 256, 0, stream>>>(h1, W2l, b2l, W2r, b2r, xl2, xr2, N_NODES);
    conv2_agg<<<(N_NODES * 32 + 255) / 256, 256, 0, stream>>>(xl2, xr2, att2, bias2,
                                                              offsets, csr_src, h2, N_NODES);
    final_linear<<<(N_NODES + 15) / 16, 256, 0, stream>>>(h2, Wlin, blin, out, N_NODES);
}